// Round 4
// baseline (284.076 us; speedup 1.0000x reference)
//
#include <hip/hip_runtime.h>
#include <hip/hip_bf16.h>

// ---------- constants ----------
#define M_ROWS   11520          // b*n = 2*5760
#define D_IN     512
#define HD       1960
#define HDP      2048           // padded hidden dim for h (multiple of 128)
#define CPAD     52             // per-cch padded channel count (49 -> 52, su4-aligned)
#define K2       2080           // 40*52, GEMM2 K (multiple of 32)
#define B2       16
#define NVECS    720            // 20*36
#define LH       20
#define LW       36
#define HH       60
#define WW       108
#define CCH      40             // 1960/49

using bf16x8 = __attribute__((ext_vector_type(8))) short;
using f32x4  = __attribute__((ext_vector_type(4))) float;
using f4     = __attribute__((ext_vector_type(4))) float;
using su4    = __attribute__((ext_vector_type(4))) unsigned short;

__device__ __forceinline__ float bf2f(unsigned short u) {
    unsigned int x = ((unsigned int)u) << 16;
    return __builtin_bit_cast(float, x);
}
__device__ __forceinline__ unsigned short f2bf(float f) {
    unsigned int x = __builtin_bit_cast(unsigned int, f);
    unsigned int r = (x + 0x7fffu + ((x >> 16) & 1u)) >> 16;
    return (unsigned short)r;
}

// async global->LDS, 16 bytes per lane (global_load_lds_dwordx4)
__device__ __forceinline__ void gl_lds16(const unsigned short* g, unsigned short* l) {
    __builtin_amdgcn_global_load_lds(
        (const __attribute__((address_space(1))) unsigned int*)g,
        (__attribute__((address_space(3))) unsigned int*)l, 16, 0, 0);
}

// ---------- x (f32, M x 512) -> xb (bf16), 4 elems/thread ----------
__global__ void conv_x4(const float* __restrict__ x, unsigned short* __restrict__ xb) {
    int t = blockIdx.x * 256 + threadIdx.x;       // total M_ROWS*512/4
    f4 v = ((const f4*)x)[t];
    su4 o;
    o.x = f2bf(v.x); o.y = f2bf(v.y); o.z = f2bf(v.z); o.w = f2bf(v.w);
    ((su4*)xb)[t] = o;
}

// ---------- W1 (f32, 512x1960) -> W1t (bf16, 2048x512) = W1^T padded; LDS transpose ----------
__global__ void pack_w1t_t(const float* __restrict__ W1, unsigned short* __restrict__ W1t) {
    __shared__ unsigned short tile[32][33];
    int blk = blockIdx.x;                         // 16 k-tiles x 64 n-tiles
    int kt = blk & 15, nt = blk >> 4;
    int k0 = kt * 32, n0 = nt * 32;
    int t = threadIdx.x;
    int tx = t & 31, ty = t >> 5;                 // ty in [0,8)
#pragma unroll
    for (int p = 0; p < 4; p++) {
        int k = k0 + ty + p * 8;                  // k < 512 always
        int n = n0 + tx;
        tile[ty + p * 8][tx] = (n < HD) ? f2bf(W1[k * HD + n]) : (unsigned short)0;
    }
    __syncthreads();
#pragma unroll
    for (int p = 0; p < 4; p++) {
        int n = n0 + ty + p * 8;                  // n < 2048 always
        int k = k0 + tx;
        W1t[n * 512 + k] = tile[tx][ty + p * 8];
    }
}

// ---------- W2 (f32, 1960x512) -> W2t (bf16, 512x2080), 52-padded K layout ----------
__global__ void pack_w2t52(const float* __restrict__ W2, unsigned short* __restrict__ W2t) {
    int idx = blockIdx.x * 256 + threadIdx.x;     // n*2080 + k, total 512*2080
    int n = idx / K2, k = idx - n * K2;
    int cch = k / CPAD, rem = k - cch * CPAD;
    W2t[idx] = (rem < 49) ? f2bf(W2[(cch * 49 + rem) * 512 + n]) : (unsigned short)0;
}

// ---------- LDS-staged GEMM: C = A(M x lda) * Bt(N x ldb)^T + bias ----------
// 128x128 block tile, 4 waves (2x2 of 64x64), BK=32, global_load_lds width=16.
// XCD-aware swizzle: blocks sharing an A-row-tile (same by) land on one XCD.
template <bool OUT_F32>
__global__ __launch_bounds__(256) void gemm_lds(
    const unsigned short* __restrict__ A,
    const unsigned short* __restrict__ Bt,
    const float* __restrict__ bias, int bias_n,
    void* __restrict__ Cv,
    int lda, int ldb, int ldc, int K, int nbx, int nby)
{
    __shared__ unsigned short sA[128 * 32];
    __shared__ unsigned short sB[128 * 32];

    int bid = blockIdx.x;
    int G = nbx * 8;
    int nfull = nby >> 3;
    int by, bx;
    if (bid < nfull * G) {
        int g = bid / G, r = bid - g * G;
        by = g * 8 + (r & 7);                     // dispatch XCD = bid%8 -> same by per XCD
        bx = r >> 3;
    } else {
        int t2 = bid - nfull * G;
        int rr = nby - nfull * 8;
        by = nfull * 8 + t2 % rr;
        bx = t2 / rr;
    }

    int t    = threadIdx.x;
    int w    = t >> 6;
    int lane = t & 63;
    int quad = lane >> 4;
    int l16  = lane & 15;

    int row0 = by * 128, col0 = bx * 128;
    int wr = (w >> 1) * 64, wc = (w & 1) * 64;

    const unsigned short* Ag = A  + (size_t)(row0 + (t >> 2)) * lda + (t & 3) * 8;
    const unsigned short* Bg = Bt + (size_t)(col0 + (t >> 2)) * ldb + (t & 3) * 8;
    unsigned short* lA0 = sA + t * 8;
    unsigned short* lA1 = sA + 2048 + t * 8;
    unsigned short* lB0 = sB + t * 8;
    unsigned short* lB1 = sB + 2048 + t * 8;

    f32x4 acc[4][4] = {};

    for (int k0 = 0; k0 < K; k0 += 32) {
        gl_lds16(Ag + k0, lA0);
        gl_lds16(Ag + (size_t)64 * lda + k0, lA1);
        gl_lds16(Bg + k0, lB0);
        gl_lds16(Bg + (size_t)64 * ldb + k0, lB1);
        __syncthreads();

        bf16x8 a[4], b[4];
#pragma unroll
        for (int i = 0; i < 4; i++)
            a[i] = *(const bf16x8*)(sA + (wr + i * 16 + l16) * 32 + quad * 8);
#pragma unroll
        for (int j = 0; j < 4; j++)
            b[j] = *(const bf16x8*)(sB + (wc + j * 16 + l16) * 32 + quad * 8);
#pragma unroll
        for (int i = 0; i < 4; i++)
#pragma unroll
            for (int j = 0; j < 4; j++)
                acc[i][j] = __builtin_amdgcn_mfma_f32_16x16x32_bf16(a[i], b[j], acc[i][j], 0, 0, 0);
        __syncthreads();
    }

#pragma unroll
    for (int j = 0; j < 4; j++) {
        int col = col0 + wc + j * 16 + l16;
        float bv = (col < bias_n) ? bias[col] : 0.0f;
#pragma unroll
        for (int i = 0; i < 4; i++) {
            int rbase = row0 + wr + i * 16 + quad * 4;
#pragma unroll
            for (int r = 0; r < 4; r++) {
                float v = acc[i][j][r] + bv;
                if (OUT_F32)
                    ((float*)Cv)[(size_t)(rbase + r) * ldc + col] = v;
                else
                    ((unsigned short*)Cv)[(size_t)(rbase + r) * ldc + col] = f2bf(v);
            }
        }
    }
}

// ---------- fold + normalize, LDS-tiled: h (M x 2048) -> y (16x40x60x108 bf16) ----------
// block = (b2, cch, p): owns y rows [15p, 15p+15); stages h strips lh in [5p-1, 5p+6)
__global__ __launch_bounds__(256) void fold_y(
    const unsigned short* __restrict__ h,
    unsigned short* __restrict__ y)
{
    __shared__ unsigned short h_lds[7 * 36 * 49];     // 24,696 B
    int bid = blockIdx.x;                             // 16*40*4 = 2560
    int p   = bid & 3;
    int cch = (bid >> 2) % CCH;
    int b2  = bid / (CCH * 4);
    int tid = threadIdx.x;

    int lh_base = 5 * p - 1;
    int lh_lo = lh_base < 0 ? 0 : lh_base;
    int lh_hi = 5 * p + 6; if (lh_hi > LH) lh_hi = LH;
    int slot0 = lh_lo - lh_base;
    int total = (lh_hi - lh_lo) * 36 * 49;
    const unsigned short* hsrc = h + (size_t)(b2 * NVECS + lh_lo * 36) * HDP + cch * 49;

    for (int idx = tid; idx < total; idx += 256) {
        int row = idx / 49, e = idx - row * 49;
        h_lds[(slot0 * 36 + row) * 49 + e] = hsrc[(size_t)row * HDP + e];
    }
    __syncthreads();

    unsigned short* yb = y + ((size_t)(b2 * CCH + cch) * HH + 15 * p) * WW;
    for (int idx = tid; idx < 15 * WW; idx += 256) {
        int rr = idx / WW, c = idx - rr * WW;
        int r = 15 * p + rr;
        int rp = r + 3, cp = c + 3;
        int n1 = 0, n2 = 0;
        int sl_v[3], k1_v[3], lw_v[3], k2_v[3];
        for (int k1 = rp % 3; k1 < 7; k1 += 3) {
            int lh = (rp - k1) / 3;
            if (lh >= 0 && lh < LH) { sl_v[n1] = lh - lh_base; k1_v[n1] = k1; n1++; }
        }
        for (int k2 = cp % 3; k2 < 7; k2 += 3) {
            int lw = (cp - k2) / 3;
            if (lw >= 0 && lw < LW) { lw_v[n2] = lw; k2_v[n2] = k2; n2++; }
        }
        float s = 0.0f;
        for (int i = 0; i < n1; i++)
            for (int j = 0; j < n2; j++)
                s += bf2f(h_lds[(sl_v[i] * 36 + lw_v[j]) * 49 + k1_v[i] * 7 + k2_v[j]]);
        yb[(size_t)rr * WW + c] = f2bf(s / (float)(n1 * n2));
    }
}

// ---------- unfold + relu into 52-padded layout: y -> uf (M x 2080) ----------
__global__ void unfold_relu52(const unsigned short* __restrict__ y,
                              unsigned short* __restrict__ uf) {
    int t = blockIdx.x * 256 + threadIdx.x;       // total M_ROWS*520 (one su4 each)
    int row = t / 520;
    int q = t - row * 520;
    int cch = q / 13;
    int j0 = (q - cch * 13) * 4;
    int b2 = row / NVECS;
    int v  = row - b2 * NVECS;
    int lh = v / LW, lw = v - lh * LW;
    int rb = 3 * lh - 3, cb = 3 * lw - 3;
    const unsigned short* yb = y + (size_t)(b2 * CCH + cch) * HH * WW;

    su4 o;
#pragma unroll
    for (int e = 0; e < 4; e++) {
        int j = j0 + e;
        unsigned short val = 0;
        if (j < 49) {
            int k1 = j / 7, k2 = j - k1 * 7;
            int r = rb + k1, cc = cb + k2;
            if ((unsigned)r < (unsigned)HH && (unsigned)cc < (unsigned)WW) {
                unsigned short u = yb[r * WW + cc];
                val = (u & 0x8000u) ? (unsigned short)0 : u;
            }
        }
        ((unsigned short*)&o)[e] = val;
    }
    *(su4*)(uf + (size_t)row * K2 + q * 4) = o;
}

// ---------- launch ----------
extern "C" void kernel_launch(void* const* d_in, const int* in_sizes, int n_in,
                              void* d_out, int out_size, void* d_ws, size_t ws_size,
                              hipStream_t stream) {
    const float* x  = (const float*)d_in[0];
    const float* W1 = (const float*)d_in[1];
    const float* b1 = (const float*)d_in[2];
    const float* W2 = (const float*)d_in[3];
    const float* b2 = (const float*)d_in[4];
    float* out = (float*)d_out;

    unsigned short* ws   = (unsigned short*)d_ws;
    unsigned short* xb   = ws;                                  // M_ROWS*512
    unsigned short* h_uf = xb + (size_t)M_ROWS * D_IN;          // max(M*2048, M*2080) = M*K2 (h, then uf)
    unsigned short* y    = h_uf + (size_t)M_ROWS * K2;          // 16*40*60*108 = 4,147,200
    unsigned short* w1t  = y + (size_t)B2 * CCH * HH * WW;      // 2048*512
    unsigned short* w2t  = w1t + (size_t)HDP * D_IN;            // 512*2080

    hipLaunchKernelGGL(conv_x4, dim3(M_ROWS * D_IN / 4 / 256), dim3(256), 0, stream, x, xb);
    hipLaunchKernelGGL(pack_w1t_t, dim3(16 * 64), dim3(256), 0, stream, W1, w1t);
    hipLaunchKernelGGL(pack_w2t52, dim3(D_IN * K2 / 256), dim3(256), 0, stream, W2, w2t);

    // GEMM1: h = x @ W1 + b1   (M=11520, N=2048, K=512), bf16 out
    hipLaunchKernelGGL((gemm_lds<false>), dim3((M_ROWS / 128) * (HDP / 128)), dim3(256), 0, stream,
                       xb, w1t, b1, HD, (void*)h_uf, D_IN, D_IN, HDP, D_IN, HDP / 128, M_ROWS / 128);

    // fold + normalize (LDS-tiled)
    hipLaunchKernelGGL(fold_y, dim3(B2 * CCH * 4), dim3(256), 0, stream, h_uf, y);

    // unfold + relu into 52-padded uf (overwrites h buffer)
    hipLaunchKernelGGL(unfold_relu52, dim3(M_ROWS * 520 / 256), dim3(256), 0, stream, y, h_uf);

    // GEMM2: out = uf @ W2 + b2   (M=11520, N=512, K=2080), f32 out
    hipLaunchKernelGGL((gemm_lds<true>), dim3((M_ROWS / 128) * (D_IN / 128)), dim3(256), 0, stream,
                       h_uf, w2t, b2, D_IN, (void*)out, K2, K2, D_IN, K2, D_IN / 128, M_ROWS / 128);
}